// Round 3
// baseline (220.833 us; speedup 1.0000x reference)
//
#include <hip/hip_runtime.h>

// Output = jacobi(X, Mask1, 100) — the multigrid sweeps in the reference are
// dead code for the returned value (grids[0] is never mutated).
// Trapezoidal temporal blocking: 10 launches x 10 fused iterations in LDS.
// Halo-ring LDS layout -> branch-free inner loop (no edge freezing needed:
// garbage at tile edges stays bounded and never reaches the central OS x OS
// output window; at true domain edges the zero halo equals the zero padding).

#define W 1024
#define H 1024
#define TILE 64
#define TI 10                    // fused iterations per launch
#define OS (TILE - 2 * TI)       // 44 valid output per tile
#define NB 24                    // ceil(1024/44)
#define LS 72                    // LDS row stride in floats; interior cols 4..67
#define LROWS 66                 // row 0 top halo, 1..64 interior, 65 bottom halo
#define NLAUNCH 10               // NLAUNCH * TI = 100

__device__ __forceinline__ void jstep(
    const float (*__restrict__ src)[LS], float (*__restrict__ dst)[LS],
    const float (&m)[4][4], int R0, int C0)
{
    float4 rv[6];
    #pragma unroll
    for (int k = 0; k < 6; ++k)
        rv[k] = *(const float4*)&src[R0 - 1 + k][C0];
    #pragma unroll
    for (int i = 0; i < 4; ++i) {
        float lsc = src[R0 + i][C0 - 1];
        float rsc = src[R0 + i][C0 + 4];
        float4 up = rv[i], ce = rv[i + 1], dn = rv[i + 2];
        float4 nv; float s;
        s = (up.x + dn.x) + (lsc  + ce.y); nv.x = fmaf(m[i][0], fmaf(0.25f, s, -ce.x), ce.x);
        s = (up.y + dn.y) + (ce.x + ce.z); nv.y = fmaf(m[i][1], fmaf(0.25f, s, -ce.y), ce.y);
        s = (up.z + dn.z) + (ce.y + ce.w); nv.z = fmaf(m[i][2], fmaf(0.25f, s, -ce.z), ce.z);
        s = (up.w + dn.w) + (ce.z + rsc ); nv.w = fmaf(m[i][3], fmaf(0.25f, s, -ce.w), ce.w);
        *(float4*)&dst[R0 + i][C0] = nv;
    }
}

__global__ __launch_bounds__(256, 4) void jacobi_trap(
    const float* __restrict__ xin, const float* __restrict__ mask,
    float* __restrict__ xout)
{
    __shared__ float A[LROWS][LS];
    __shared__ float B[LROWS][LS];

    const int tid = threadIdx.x;
    const int gx0 = (int)blockIdx.x * OS - TI;
    const int gy0 = (int)blockIdx.y * OS - TI;

    // zero the halo ring of both buffers (only row 0, row 65, col 3, col 68
    // are ever read as halo)
    if (tid < LS) {
        A[0][tid] = 0.f; A[LROWS - 1][tid] = 0.f;
        B[0][tid] = 0.f; B[LROWS - 1][tid] = 0.f;
    }
    if (tid >= 64 && tid < 128) {
        int r = tid - 63;                       // 1..64
        A[r][3] = 0.f; B[r][3] = 0.f;
        A[r][68] = 0.f; B[r][68] = 0.f;
    }

    // load 64x64 x tile into interior (zeros outside domain), coalesced rows
    #pragma unroll
    for (int k = 0; k < 16; ++k) {
        int idx = tid + k * 256;
        int r = idx >> 6, c = idx & 63;
        int gr = gy0 + r, gc = gx0 + c;
        float v = 0.f;
        if ((unsigned)gr < (unsigned)H && (unsigned)gc < (unsigned)W)
            v = xin[gr * W + gc];
        A[r + 1][c + 4] = v;
    }

    // mask for my 4x4 patch -> registers (reused across all TI iterations)
    const int pr = tid >> 4, pc = tid & 15;
    const int R0 = pr * 4 + 1;                  // LDS interior row
    const int C0 = pc * 4 + 4;                  // LDS interior col
    float m[4][4];
    #pragma unroll
    for (int i = 0; i < 4; ++i) {
        #pragma unroll
        for (int j = 0; j < 4; ++j) {
            int gr = gy0 + (R0 - 1) + i, gc = gx0 + (C0 - 4) + j;
            m[i][j] = ((unsigned)gr < (unsigned)H && (unsigned)gc < (unsigned)W)
                        ? mask[gr * W + gc] : 0.f;
        }
    }

    __syncthreads();

    #pragma unroll 1
    for (int it = 0; it < TI / 2; ++it) {
        jstep(A, B, m, R0, C0);
        __syncthreads();
        jstep(B, A, m, R0, C0);
        __syncthreads();
    }

    // TI even -> result in A; write central OS x OS window
    #pragma unroll
    for (int i = 0; i < 4; ++i) {
        int lr = (R0 - 1) + i;                  // tile-local 0..63
        if (lr < TI || lr >= TILE - TI) continue;
        int gr = gy0 + lr;
        if ((unsigned)gr >= (unsigned)H) continue;
        #pragma unroll
        for (int j = 0; j < 4; ++j) {
            int lc = (C0 - 4) + j;
            if (lc < TI || lc >= TILE - TI) continue;
            int gc = gx0 + lc;
            if ((unsigned)gc >= (unsigned)W) continue;
            xout[gr * W + gc] = A[R0 + i][C0 + j];
        }
    }
}

extern "C" void kernel_launch(void* const* d_in, const int* in_sizes, int n_in,
                              void* d_out, int out_size, void* d_ws, size_t ws_size,
                              hipStream_t stream) {
    const float* X = (const float*)d_in[0];   // (1,1,1024,1024)
    const float* M = (const float*)d_in[1];   // Mask1
    float* out = (float*)d_out;
    float* ws  = (float*)d_ws;                // 4 MB ping buffer

    dim3 grid(NB, NB), block(256);
    // l=0: X->ws; alternate; l=9 (odd) -> out. Every buffer written before read.
    const float* src = X;
    for (int l = 0; l < NLAUNCH; ++l) {
        float* dst = (l & 1) ? out : ws;
        jacobi_trap<<<grid, block, 0, stream>>>(src, M, dst);
        src = dst;
    }
}

// Round 4
// 142.145 us; speedup vs baseline: 1.5536x; 1.5536x over previous
//
#include <hip/hip_runtime.h>

// Output = jacobi(X, Mask1, 100) — the multigrid sweeps in the reference are
// dead code for the returned value (grids[0] is never mutated).
//
// Trapezoidal temporal blocking, register-resident: 10 launches x 10 fused
// iterations. Each thread keeps its 4x4 cell patch + mask in registers for
// all 10 iterations; LDS holds only per-patch edge strips (double-buffered,
// 1 barrier/iter). Tile edges compute garbage that never reaches the central
// 44x44 output window (light-cone argument); the zeroed strip ring doubles
// as the true zero padding at domain boundaries.

#define W 1024
#define H 1024
#define TILE 64
#define TI 10                    // fused iterations per launch
#define OS (TILE - 2 * TI)       // 44 valid output per tile
#define NB 24                    // ceil(1024/44)
#define NLAUNCH 10               // NLAUNCH * TI = 100
#define SR 18                    // strip dim: 16 patches + guard ring

#define S_T 0
#define S_B 1
#define S_L 2
#define S_R 3

__device__ __forceinline__ float2 ld2(const float* __restrict__ p, int gr, int gc) {
    // gc is always even and W is even -> the pair is entirely in or out of [0,W)
    if ((unsigned)gr < (unsigned)H && (unsigned)gc < (unsigned)W)
        return *(const float2*)&p[gr * W + gc];
    return make_float2(0.f, 0.f);
}

__device__ __forceinline__ float4 rowstep(const float4 up, const float4 ce,
                                          const float4 dn, const float lf,
                                          const float rt, const float4 m) {
    float4 s, n;
    s.x = (up.x + dn.x) + (lf   + ce.y);
    s.y = (up.y + dn.y) + (ce.x + ce.z);
    s.z = (up.z + dn.z) + (ce.y + ce.w);
    s.w = (up.w + dn.w) + (ce.z + rt);
    n.x = fmaf(m.x, fmaf(0.25f, s.x, -ce.x), ce.x);
    n.y = fmaf(m.y, fmaf(0.25f, s.y, -ce.y), ce.y);
    n.z = fmaf(m.z, fmaf(0.25f, s.z, -ce.z), ce.z);
    n.w = fmaf(m.w, fmaf(0.25f, s.w, -ce.w), ce.w);
    return n;
}

__device__ __forceinline__ void one_iter(
    float4 (* __restrict__ rs)[SR][SR], float4 (* __restrict__ ws)[SR][SR],
    int pr, int pc,
    float4& c0, float4& c1, float4& c2, float4& c3,
    const float4 m0, const float4 m1, const float4 m2, const float4 m3)
{
    const float4 th = rs[S_B][pr    ][pc + 1];   // patch above's bottom row
    const float4 bh = rs[S_T][pr + 2][pc + 1];   // patch below's top row
    const float4 lh = rs[S_R][pr + 1][pc    ];   // left patch's right col
    const float4 rh = rs[S_L][pr + 1][pc + 2];   // right patch's left col

    const float4 n0 = rowstep(th, c0, c1, lh.x, rh.x, m0);
    const float4 n1 = rowstep(c0, c1, c2, lh.y, rh.y, m1);
    const float4 n2 = rowstep(c1, c2, c3, lh.z, rh.z, m2);
    const float4 n3 = rowstep(c2, c3, bh, lh.w, rh.w, m3);

    ws[S_T][pr + 1][pc + 1] = n0;
    ws[S_B][pr + 1][pc + 1] = n3;
    ws[S_L][pr + 1][pc + 1] = make_float4(n0.x, n1.x, n2.x, n3.x);
    ws[S_R][pr + 1][pc + 1] = make_float4(n0.w, n1.w, n2.w, n3.w);

    __syncthreads();
    c0 = n0; c1 = n1; c2 = n2; c3 = n3;
}

__global__ __launch_bounds__(256, 4) void jacobi_trap(
    const float* __restrict__ xin, const float* __restrict__ mask,
    float* __restrict__ xout)
{
    __shared__ float4 strips[2][4][SR][SR];

    const int tid = threadIdx.x;
    const int pr = tid >> 4, pc = tid & 15;
    const int gx0 = (int)blockIdx.x * OS - TI;
    const int gy0 = (int)blockIdx.y * OS - TI;
    const int gr0 = gy0 + pr * 4;
    const int gc0 = gx0 + pc * 4;               // always even

    // zero both strip buffers (guard ring must be 0; interior overwritten)
    {
        float4* s = &strips[0][0][0][0];
        const int tot = 2 * 4 * SR * SR;        // 2592
        #pragma unroll
        for (int k = 0; k < 11; ++k) {
            int idx = tid + k * 256;
            if (idx < tot) s[idx] = make_float4(0.f, 0.f, 0.f, 0.f);
        }
    }

    // load 4x4 cells + mask into registers (float2 pairs, 8B-aligned)
    float4 c0, c1, c2, c3, m0, m1, m2, m3;
    {
        float4 cc[4], mm[4];
        #pragma unroll
        for (int i = 0; i < 4; ++i) {
            int gr = gr0 + i;
            float2 a = ld2(xin, gr, gc0), b = ld2(xin, gr, gc0 + 2);
            cc[i] = make_float4(a.x, a.y, b.x, b.y);
            float2 p = ld2(mask, gr, gc0), q = ld2(mask, gr, gc0 + 2);
            mm[i] = make_float4(p.x, p.y, q.x, q.y);
        }
        c0 = cc[0]; c1 = cc[1]; c2 = cc[2]; c3 = cc[3];
        m0 = mm[0]; m1 = mm[1]; m2 = mm[2]; m3 = mm[3];
    }

    __syncthreads();   // zero-fill visible before edge publish

    // publish initial edges into buffer 0
    strips[0][S_T][pr + 1][pc + 1] = c0;
    strips[0][S_B][pr + 1][pc + 1] = c3;
    strips[0][S_L][pr + 1][pc + 1] = make_float4(c0.x, c1.x, c2.x, c3.x);
    strips[0][S_R][pr + 1][pc + 1] = make_float4(c0.w, c1.w, c2.w, c3.w);
    __syncthreads();

    #pragma unroll 1
    for (int it = 0; it < TI / 2; ++it) {
        one_iter(strips[0], strips[1], pr, pc, c0, c1, c2, c3, m0, m1, m2, m3);
        one_iter(strips[1], strips[0], pr, pc, c0, c1, c2, c3, m0, m1, m2, m3);
    }

    // store central OS x OS window (float2 pairs; pair is in/out together)
    #pragma unroll
    for (int i = 0; i < 4; ++i) {
        int lr = pr * 4 + i;
        if (lr < TI || lr >= TILE - TI) continue;
        int gr = gy0 + lr;
        if ((unsigned)gr >= (unsigned)H) continue;
        const float4 ci = (i == 0) ? c0 : (i == 1) ? c1 : (i == 2) ? c2 : c3;
        int lc0 = pc * 4, gc = gx0 + lc0;
        if (lc0 >= TI && lc0 < TILE - TI && (unsigned)gc < (unsigned)W)
            *(float2*)&xout[gr * W + gc] = make_float2(ci.x, ci.y);
        int lc2 = lc0 + 2, gc2 = gx0 + lc2;
        if (lc2 >= TI && lc2 < TILE - TI && (unsigned)gc2 < (unsigned)W)
            *(float2*)&xout[gr * W + gc2] = make_float2(ci.z, ci.w);
    }
}

extern "C" void kernel_launch(void* const* d_in, const int* in_sizes, int n_in,
                              void* d_out, int out_size, void* d_ws, size_t ws_size,
                              hipStream_t stream) {
    const float* X = (const float*)d_in[0];   // (1,1,1024,1024)
    const float* M = (const float*)d_in[1];   // Mask1
    float* out = (float*)d_out;
    float* ws  = (float*)d_ws;                // 4 MB ping buffer

    dim3 grid(NB, NB), block(256);
    // l=0: X->ws; alternate; l=9 (odd) -> out. Every central window union
    // covers the full domain, so ws/out are fully written before any read.
    const float* src = X;
    for (int l = 0; l < NLAUNCH; ++l) {
        float* dst = (l & 1) ? out : ws;
        jacobi_trap<<<grid, block, 0, stream>>>(src, M, dst);
        src = dst;
    }
}